// Round 8
// baseline (562.188 us; speedup 1.0000x reference)
//
#include <hip/hip_runtime.h>
#include <math.h>

#define Bsz 1024
#define Npt 50
#define Hd 128
#define G4 512
#define Tt 50
#define NEGC 1000000000.0f
#define CTANH 10.0f
#define L2E 1.44269504088896340736f
#define TL2E (2.0f * L2E)

#define OFF_R 0
#define OFF_V 1024
#define OFF_LP 2048
#define OFF_A 2562048
#define OFF_C 2613248
#define OFF_P 2715648

// ws float offsets (all tables; no bulk state)
#define WS_TG 0        // 128 float4 {Mg0, Mg1, vg, cg}
#define WS_TP 512      // 128 float4 {Mp0, Mp1, vp, cp}
#define WS_TQ 1024     // 128 float4 {Pg0, Pg1, cg@Wqp+cp, 0}
#define WS_A0 1536     // 512: We0@Wi
#define WS_A1 2048     // 512: We1@Wi
#define WS_A2 2560     // 512: bemb@Wi + bl
#define WS_A3 3072     // 512: dec_init@Wi + bl   (step 0)
#define WS_CT 3584     // 128 float4 {T0, T1, Tc(+b1), W2}

typedef __attribute__((ext_vector_type(8))) short s16x8;
typedef __attribute__((ext_vector_type(4))) float fx4;

// raw v_exp_f32: D = 2^S0 (no hidden log2e multiply)
__device__ __forceinline__ float fexp2(float x) {
  float r;
  asm("v_exp_f32 %0, %1" : "=v"(r) : "v"(x));
  return r;
}

__device__ __forceinline__ float fsig(float x) {
  return __builtin_amdgcn_rcpf(1.0f + __expf(-x));
}

__device__ __forceinline__ float ftanh(float x) {
  float e = __expf(2.0f * x);
  return 1.0f - 2.0f * __builtin_amdgcn_rcpf(e + 1.0f);
}

// fp32 -> bf16 bits, round-to-nearest-even (finite inputs)
__device__ __forceinline__ unsigned short f2bf(float x) {
  unsigned int u = __float_as_uint(x);
  unsigned int r = (u + 0x7fffu + ((u >> 16) & 1u)) >> 16;
  return (unsigned short)r;
}
__device__ __forceinline__ float bf2f(unsigned short b) {
  return __uint_as_float(((unsigned int)b) << 16);
}

__device__ __forceinline__ float dpp_sum_bcast(float x) {
  int v;
  v = __builtin_amdgcn_update_dpp(0, __float_as_int(x), 0x111, 0xf, 0xf, true);
  x += __int_as_float(v);
  v = __builtin_amdgcn_update_dpp(0, __float_as_int(x), 0x112, 0xf, 0xf, true);
  x += __int_as_float(v);
  v = __builtin_amdgcn_update_dpp(0, __float_as_int(x), 0x114, 0xf, 0xf, true);
  x += __int_as_float(v);
  v = __builtin_amdgcn_update_dpp(0, __float_as_int(x), 0x118, 0xf, 0xf, true);
  x += __int_as_float(v);
  v = __builtin_amdgcn_update_dpp(0, __float_as_int(x), 0x142, 0xf, 0xf, true);
  x += __int_as_float(v);
  v = __builtin_amdgcn_update_dpp(0, __float_as_int(x), 0x143, 0xf, 0xf, true);
  x += __int_as_float(v);
  return __int_as_float(__builtin_amdgcn_readlane(__float_as_int(x), 63));
}

// wave64 max via DPP; REQUIRES x >= 0
__device__ __forceinline__ float dpp_max_bcast(float x) {
  int v;
  v = __builtin_amdgcn_update_dpp(0, __float_as_int(x), 0x111, 0xf, 0xf, true);
  x = fmaxf(x, __int_as_float(v));
  v = __builtin_amdgcn_update_dpp(0, __float_as_int(x), 0x112, 0xf, 0xf, true);
  x = fmaxf(x, __int_as_float(v));
  v = __builtin_amdgcn_update_dpp(0, __float_as_int(x), 0x114, 0xf, 0xf, true);
  x = fmaxf(x, __int_as_float(v));
  v = __builtin_amdgcn_update_dpp(0, __float_as_int(x), 0x118, 0xf, 0xf, true);
  x = fmaxf(x, __int_as_float(v));
  v = __builtin_amdgcn_update_dpp(0, __float_as_int(x), 0x142, 0xf, 0xf, true);
  x = fmaxf(x, __int_as_float(v));
  v = __builtin_amdgcn_update_dpp(0, __float_as_int(x), 0x143, 0xf, 0xf, true);
  x = fmaxf(x, __int_as_float(v));
  return __int_as_float(__builtin_amdgcn_readlane(__float_as_int(x), 63));
}

__device__ __forceinline__ float xsum(float x) {
  #pragma unroll
  for (int off = 32; off >= 1; off >>= 1) x += __shfl_xor(x, off, 64);
  return x;
}

// One block, 512 threads: all rank-2 tables + collapsed critic tables.
__global__ __launch_bounds__(512) void k_pre(const float* __restrict__ Wemb,
                                             const float* __restrict__ bemb,
                                             const float* __restrict__ dinit,
                                             const float* __restrict__ Wi,
                                             const float* __restrict__ bl,
                                             const float* __restrict__ Wqp,
                                             const float* __restrict__ Wrg,
                                             const float* __restrict__ Wrp,
                                             const float* __restrict__ vg,
                                             const float* __restrict__ vp,
                                             const float* __restrict__ Wrc,
                                             const float* __restrict__ W1,
                                             const float* __restrict__ b1,
                                             const float* __restrict__ W2,
                                             float* __restrict__ ws) {
  __shared__ float mg_s[2][128], mp_s[2][128], cg_s[128], cp_s[128];
  __shared__ float pg_s[2][128], pc_s[128];
  __shared__ float r0_s[128], r1_s[128], rc_s[128];
  int t = threadIdx.x;
  if (t < 256) {
    int j = t >> 7, hh = t & 127;
    float ag = 0.f, ap = 0.f;
    for (int k = 0; k < 128; ++k) {
      float we = Wemb[j * 128 + k];
      ag = fmaf(we, Wrg[k * 128 + hh], ag);
      ap = fmaf(we, Wrp[k * 128 + hh], ap);
    }
    mg_s[j][hh] = ag; mp_s[j][hh] = ap;
  } else if (t < 384) {
    int hh = t & 127;
    float cgv = 0.f, cpv = 0.f;
    for (int k = 0; k < 128; ++k) {
      float be = bemb[k];
      cgv = fmaf(be, Wrg[k * 128 + hh], cgv);
      cpv = fmaf(be, Wrp[k * 128 + hh], cpv);
    }
    cg_s[hh] = cgv; cp_s[hh] = cpv;
  } else {
    int hh = t & 127;
    float a0 = 0.f, a1 = 0.f, ac = 0.f;
    for (int k = 0; k < 128; ++k) {
      float wr = Wrc[k * 128 + hh];
      a0 = fmaf(Wemb[k], wr, a0);
      a1 = fmaf(Wemb[128 + k], wr, a1);
      ac = fmaf(bemb[k], wr, ac);
    }
    r0_s[hh] = a0; r1_s[hh] = a1; rc_s[hh] = ac;
  }
  __syncthreads();
  if (t < 256) {
    int j = t >> 7, hh = t & 127;
    float pg = 0.f;
    for (int k = 0; k < 128; ++k) pg = fmaf(mg_s[j][k], Wqp[k * 128 + hh], pg);
    pg_s[j][hh] = pg;
  } else if (t < 384) {
    int hh = t & 127;
    float pcv = 0.f;
    for (int k = 0; k < 128; ++k) pcv = fmaf(cg_s[k], Wqp[k * 128 + hh], pcv);
    pc_s[hh] = pcv + cp_s[hh];
  } else {
    int hh = t & 127;
    float t0 = 0.f, t1 = 0.f, tc = 0.f;
    for (int k = 0; k < 128; ++k) {
      float w1 = W1[k * 128 + hh];
      t0 = fmaf(r0_s[k], w1, t0);
      t1 = fmaf(r1_s[k], w1, t1);
      tc = fmaf(rc_s[k], w1, tc);
    }
    float4* w4 = (float4*)ws;
    w4[WS_CT / 4 + hh] = make_float4(t0, t1, tc + b1[hh], W2[hh]);
  }
  __syncthreads();
  if (t < 128) {
    float4* w4 = (float4*)ws;
    w4[WS_TG / 4 + t] = make_float4(mg_s[0][t], mg_s[1][t], vg[t], cg_s[t]);
    w4[WS_TP / 4 + t] = make_float4(mp_s[0][t], mp_s[1][t], vp[t], cp_s[t]);
    w4[WS_TQ / 4 + t] = make_float4(pg_s[0][t], pg_s[1][t], pc_s[t], 0.f);
  }
  {
    int j = t;
    float a0 = 0.f, a1 = 0.f, a2 = 0.f, a3 = 0.f;
    for (int k = 0; k < 128; ++k) {
      float wi = Wi[k * G4 + j];
      a0 = fmaf(Wemb[k], wi, a0);
      a1 = fmaf(Wemb[128 + k], wi, a1);
      a2 = fmaf(bemb[k], wi, a2);
      a3 = fmaf(dinit[k], wi, a3);
    }
    ws[WS_A0 + j] = a0;
    ws[WS_A1 + j] = a1;
    ws[WS_A2 + j] = a2 + bl[j];
    ws[WS_A3 + j] = a3 + bl[j];
  }
}

// Persistent: 256 blocks x 1024 threads (16 waves), 4 rows/block.
// r6 base + r7/r8: q = h2@Wqg moved onto the MFMA pass (r5-verified 4-term
// bf16 split). P3 / qpart / P4a / h_s deleted:
//  - P2 threads scatter-write h2 directly as bf16 hi/lo A-fragments
//    (afrag rows 4-15 zero; D rows 4-15 unused).
//  - MFMA region after G_b: waves 0-7 own one 16-col Wqg tile (Bq regs,
//    single qd chain) and write rowtg.z = 2L*cg + 2L*q; all waves run the
//    gate chains (d0/d1), guarded s+1<Tt.
//  - VGPR discipline (r8): ah/al re-read from LDS per K-step in BOTH the
//    q chain and gate chains -> peak live ~120 < 128 cap (r7 had ~136).
//  - rowtg/rowtp prebuilt ({x,y,*,w} step-invariant); only word2 (qs)
//    updated per step. gates D-regs written to gates_s at step end.
//  - syncs/step: 3 block barriers + 3 row-group lsyncs.
__global__ __launch_bounds__(1024, 4) void k_mega(const float* __restrict__ ip,
                                                  const float* __restrict__ Wh,
                                                  const float* __restrict__ Wqg,
                                                  const float* __restrict__ b2,
                                                  const float* __restrict__ ws,
                                                  float* __restrict__ out) {
  __shared__ __align__(16) float gates_s[4][G4];      // 8 KB complete gates
  __shared__ s16x8 afrag_s[4][2][64];                 // 8 KB A hi/lo frags
  __shared__ __align__(16) float4 rowtg_s[4][132];    // 8.25 KB glimpse tbl
  __shared__ __align__(16) float4 rowtp_s[4][132];    // 8.25 KB pointer tbl
  __shared__ __align__(16) float up_s[4][5][64];      // 5 KB glimpse partials
  __shared__ __align__(16) float up2_s[4][5][64];     // 5 KB pointer partials
  __shared__ __align__(16) float c_s[4][Hd];          // LSTM cell state
  __shared__ float tgw_s[Hd];                         // 2L*cg (q bias)
  __shared__ __align__(16) float tq_s[G4];            // {2L Pg0,2L Pg1,2L pc,0}
  __shared__ __align__(16) float ct_s[G4];
  __shared__ __align__(16) float a0_s[G4], a1_s[G4], a2_s[G4], a3_s[G4];
  __shared__ float vt_s[2];                           // full sum(v) g/p
  __shared__ __align__(16) float ip_s[4][Npt * 2];
  __shared__ float mask_s[4][Npt];
  __shared__ float ch_s[4][Npt * 2];
  __shared__ float sel_s[4][2];
  __shared__ int ctr_s[4];                            // group rendezvous

  int t = threadIdx.x, blk = blockIdx.x;
  int w = t >> 6, lane = t & 63;

  // ---- register-resident weights ----
  // Gates B: wave w owns N-cols [32w,32w+32) as 2 tiles x 4 K-steps, hi/lo.
  // (g=lane>>4, j) <-> k = ks*32 + g*8 + j (A uses the same map).
  s16x8 Bh[2][4], Bl[2][4];
  {
    int cb = (w << 5) + (lane & 15);
    int g8 = (lane >> 4) << 3;
    #pragma unroll
    for (int tt = 0; tt < 2; ++tt)
      #pragma unroll
      for (int ks = 0; ks < 4; ++ks)
        #pragma unroll
        for (int j = 0; j < 8; ++j) {
          float x = Wh[(size_t)((ks << 5) + g8 + j) * G4 + cb + (tt << 4)];
          unsigned short hb = f2bf(x);
          Bh[tt][ks][j] = (short)hb;
          Bl[tt][ks][j] = (short)f2bf(x - bf2f(hb));
        }
  }
  // q B: wave w<8 owns Wqg cols [16w,16w+16), 1 tile x 4 K-steps, hi/lo.
  s16x8 Bqh[4], Bql[4];
  if (w < 8) {
    int cb = (w << 4) + (lane & 15);
    int g8 = (lane >> 4) << 3;
    #pragma unroll
    for (int ks = 0; ks < 4; ++ks)
      #pragma unroll
      for (int j = 0; j < 8; ++j) {
        float x = Wqg[(size_t)((ks << 5) + g8 + j) * Hd + cb];
        unsigned short hb = f2bf(x);
        Bqh[ks][j] = (short)hb;
        Bql[ks][j] = (short)f2bf(x - bf2f(hb));
      }
  }

  // ---- stage tables + per-block state ----
  const float4* ws4 = (const float4*)ws;
  if (t < 128) {
    float4 g4 = ws4[WS_TG / 4 + t];
    tgw_s[t] = TL2E * g4.w;
    float4 q4 = ws4[WS_TQ / 4 + t];
    ((float4*)tq_s)[t] = make_float4(TL2E * q4.x, TL2E * q4.y, TL2E * q4.z, 0.f);
    ((float4*)ct_s)[t] = ws4[WS_CT / 4 + t];
  } else if (t < 256) {
    int i = t - 128;
    ((float4*)a0_s)[i] = ((const float4*)(ws + WS_A0))[i];
    ((float4*)a1_s)[i] = ((const float4*)(ws + WS_A1))[i];
    ((float4*)a2_s)[i] = ((const float4*)(ws + WS_A2))[i];
    ((float4*)a3_s)[i] = ((const float4*)(ws + WS_A3))[i];
  }
  if (t < 512) {
    int r = t >> 7, hh = t & 127;
    float4 g4 = ws4[WS_TG / 4 + hh];
    rowtg_s[r][hh] = make_float4(TL2E * g4.x, TL2E * g4.y, 0.f, -2.f * g4.z);
    float4 p4 = ws4[WS_TP / 4 + hh];
    rowtp_s[r][hh] = make_float4(TL2E * p4.x, TL2E * p4.y, 0.f, -2.f * p4.z);
    c_s[r][hh] = 0.f;
    ((s16x8*)afrag_s)[t] = (s16x8)(short)0;   // rows>=4 stay zero forever
  }
  ((float2*)gates_s)[t] = make_float2(0.f, 0.f);   // gates(0) = h0@Wh = 0
  if (t < 200) {
    ((float2*)ip_s)[t] = ((const float2*)ip)[blk * 200 + t];
    ((float*)mask_s)[t] = 0.f;
  }
  if (t < 2) {         // full vsum (raw v from ws tables)
    float sv = 0.f;
    for (int hp = 0; hp < 128; ++hp)
      sv += ws[(t ? WS_TP : WS_TG) + hp * 4 + 2];
    vt_s[t] = sv;
  }
  if (t < 16) {        // zero pad rows 128..131 (a=0 -> z=0 -> +0)
    rowtg_s[t >> 2][128 + (t & 3)] = make_float4(0.f, 0.f, 0.f, 0.f);
    rowtp_s[t >> 2][128 + (t & 3)] = make_float4(0.f, 0.f, 0.f, 0.f);
  }
  if (t < 8) ((float*)sel_s)[t] = 0.f;
  if (t < 4) ctr_s[t] = 0;
  __syncthreads();

  // C/DE/F wave roles: row = w&3, hc = w>>2. Score-loop repacking:
  // flat id ell in row-group -> (rep, n2), h-range [26*rep, 26*rep+26).
  int cr = w & 3, hc = w >> 2;
  int ell = hc * 64 + lane;
  int rep = ell / 50;
  bool act = ell < 250;
  int n2 = ell - rep * 50;
  int h0 = rep * 26;
  float2 pw = make_float2(0.f, 0.f);
  if (act) pw = ((float2*)ip_s)[cr * Npt + n2];
  float2 pnl = make_float2(0.f, 0.f);
  if (lane < Npt) pnl = ((float2*)ip_s)[cr * Npt + lane];

  int lt = 0;  // rendezvous target (monotone, +4 per lsync)
  auto lsync = [&]() {
    lt += 4;
    if (lane == 0)
      __hip_atomic_fetch_add(&ctr_s[cr], 1, __ATOMIC_RELEASE,
                             __HIP_MEMORY_SCOPE_WORKGROUP);
    while (__hip_atomic_load(&ctr_s[cr], __ATOMIC_ACQUIRE,
                             __HIP_MEMORY_SCOPE_WORKGROUP) < lt)
      __builtin_amdgcn_s_sleep(1);
  };

  for (int s = 0; s < Tt; ++s) {
    __syncthreads();   // G_a: gates_s(s) + sel/mask(s-1) ready
    // ---- P2: rank-2 x-part + gates + LSTM cell + afrag write (t<512) ----
    if (t < 512) {
      int r = t >> 7, hh = t & 127;
      float p0 = sel_s[r][0], p1 = sel_s[r][1];
      float g[4];
      #pragma unroll
      for (int gi = 0; gi < 4; ++gi) {
        int j = gi * 128 + hh;
        float x = (s == 0) ? a3_s[j]
                           : fmaf(p0, a0_s[j], fmaf(p1, a1_s[j], a2_s[j]));
        g[gi] = x + gates_s[r][j];
      }
      float c2 = fsig(g[1]) * c_s[r][hh] + fsig(g[0]) * ftanh(g[2]);
      float h2 = fsig(g[3]) * ftanh(c2);
      c_s[r][hh] = c2;
      // scatter h2 as bf16 hi/lo A-fragment: k=hh -> (ks,g,j), lane=g*16+r
      int ks = hh >> 5, gg = (hh >> 3) & 3, j = hh & 7, la = gg * 16 + r;
      unsigned short hb = f2bf(h2);
      ((short*)&afrag_s[ks][0][la])[j] = (short)hb;
      ((short*)&afrag_s[ks][1][la])[j] = (short)f2bf(h2 - bf2f(hb));
    }
    __syncthreads();   // G_b: afrag ready
    // ---- MFMA region: q (w<8) + gate chains (all waves) ----
    fx4 d0 = {0.f, 0.f, 0.f, 0.f}, d1 = {0.f, 0.f, 0.f, 0.f};
    {
      if (w < 8) {     // q = h2 @ Wqg, single accumulator chain
        fx4 qd = {0.f, 0.f, 0.f, 0.f};
        #pragma unroll
        for (int ks = 0; ks < 4; ++ks) {
          s16x8 ah = afrag_s[ks][0][lane];
          s16x8 al = afrag_s[ks][1][lane];
          qd = __builtin_amdgcn_mfma_f32_16x16x32_bf16(ah, Bqh[ks], qd, 0, 0, 0);
          qd = __builtin_amdgcn_mfma_f32_16x16x32_bf16(ah, Bql[ks], qd, 0, 0, 0);
          qd = __builtin_amdgcn_mfma_f32_16x16x32_bf16(al, Bqh[ks], qd, 0, 0, 0);
          qd = __builtin_amdgcn_mfma_f32_16x16x32_bf16(al, Bql[ks], qd, 0, 0, 0);
        }
        if (lane < 16) {     // D: col=lane&15, rows 0-3 = reg 0-3
          int hcol = (w << 4) + lane;
          float tw = tgw_s[hcol];
          #pragma unroll
          for (int rr = 0; rr < 4; ++rr)
            ((float*)&rowtg_s[rr][hcol])[2] = fmaf(TL2E, qd[rr], tw);
        }
      }
      if (s + 1 < Tt) {      // gates(s+1) = h2 @ Wh, 2 interleaved chains
        #pragma unroll
        for (int ks = 0; ks < 4; ++ks) {
          s16x8 ah = afrag_s[ks][0][lane];
          s16x8 al = afrag_s[ks][1][lane];
          d0 = __builtin_amdgcn_mfma_f32_16x16x32_bf16(ah, Bh[0][ks], d0, 0, 0, 0);
          d1 = __builtin_amdgcn_mfma_f32_16x16x32_bf16(ah, Bh[1][ks], d1, 0, 0, 0);
          d0 = __builtin_amdgcn_mfma_f32_16x16x32_bf16(ah, Bl[0][ks], d0, 0, 0, 0);
          d1 = __builtin_amdgcn_mfma_f32_16x16x32_bf16(ah, Bl[1][ks], d1, 0, 0, 0);
          d0 = __builtin_amdgcn_mfma_f32_16x16x32_bf16(al, Bh[0][ks], d0, 0, 0, 0);
          d1 = __builtin_amdgcn_mfma_f32_16x16x32_bf16(al, Bh[1][ks], d1, 0, 0, 0);
          d0 = __builtin_amdgcn_mfma_f32_16x16x32_bf16(al, Bl[0][ks], d0, 0, 0, 0);
          d1 = __builtin_amdgcn_mfma_f32_16x16x32_bf16(al, Bl[1][ks], d1, 0, 0, 0);
        }
      }
    }
    __syncthreads();   // G_c: rowtg.qs ready (gate MFMAs drain in background)
    // ---- P4b: glimpse score loop (repacked lanes) ----
    if (act) {
      float ac = 0.f;
      #pragma unroll 13
      for (int i = 0; i < 26; ++i) {
        float4 f4 = rowtg_s[cr][h0 + i];
        float a = fmaf(pw.x, f4.x, fmaf(pw.y, f4.y, f4.z));
        ac = fmaf(f4.w, __builtin_amdgcn_rcpf(fexp2(a) + 1.0f), ac);
      }
      up_s[cr][rep][n2] = ac;
    }
    lsync();           // up partials ready
    // ---- P5a: glimpse softmax (dup/wave) + pointer qs2 write ----
    {
      float u = vt_s[0] + up_s[cr][0][lane] + up_s[cr][1][lane]
              + up_s[cr][2][lane] + up_s[cr][3][lane] + up_s[cr][4][lane];
      float e = 0.f;
      if (lane < Npt) e = __expf(u - NEGC * mask_s[cr][lane]);
      float ssum = dpp_sum_bcast(e);
      float sx = dpp_sum_bcast(e * pnl.x);
      float sy = dpp_sum_bcast(e * pnl.y);
      float inv = __builtin_amdgcn_rcpf(ssum);
      float s0 = sx * inv;
      float s1 = sy * inv;
      if (lane < 32) {
        int h = hc * 32 + lane;
        float4 tq4 = ((float4*)tq_s)[h];
        float qs2 = fmaf(s0, tq4.x, fmaf(s1, tq4.y, tq4.z));
        ((float*)&rowtp_s[cr][h])[2] = qs2;
      }
    }
    lsync();           // rowtp.qs2 ready
    // ---- P5b: pointer score loop (repacked lanes) ----
    if (act) {
      float ac = 0.f;
      #pragma unroll 13
      for (int i = 0; i < 26; ++i) {
        float4 f4 = rowtp_s[cr][h0 + i];
        float a = fmaf(pw.x, f4.x, fmaf(pw.y, f4.y, f4.z));
        ac = fmaf(f4.w, __builtin_amdgcn_rcpf(fexp2(a) + 1.0f), ac);
      }
      up2_s[cr][rep][n2] = ac;
    }
    lsync();           // up2 partials ready
    // ---- F(s): pointer softmax + argmax + outputs, one wave per row ----
    if (hc == 3) {
      int row = cr, b = blk * 4 + row;
      float u = vt_s[1] + up2_s[row][0][lane] + up2_s[row][1][lane]
              + up2_s[row][2][lane] + up2_s[row][3][lane]
              + up2_s[row][4][lane];
      float x = 0.f, e = 0.f;
      if (lane < Npt) {
        x = CTANH * ftanh(u) - NEGC * mask_s[row][lane];
        e = __expf(x);
      }
      float ssum = dpp_sum_bcast(e);
      float ls = __logf(ssum);
      float prob = e * __builtin_amdgcn_rcpf(ssum);
      if (lane < Npt) {
        out[OFF_LP + ((size_t)b * Tt + s) * Npt + lane] = x - ls;
        out[OFF_P + ((size_t)b * Tt + s) * Npt + lane] = prob;
      }
      float mx = dpp_max_bcast(prob);
      unsigned long long bal = __ballot((prob == mx) && (lane < Npt));
      int a = __ffsll(bal) - 1;      // first-index tie-break
      float p0a = ip_s[row][2 * a];
      float p1a = ip_s[row][2 * a + 1];
      if (lane == 0) {
        out[OFF_A + (size_t)b * Tt + s] = (float)a;
        out[OFF_C + ((size_t)b * Tt + s) * 2 + 0] = p0a;
        out[OFF_C + ((size_t)b * Tt + s) * 2 + 1] = p1a;
        ((float2*)ch_s)[row * Npt + s] = make_float2(p0a, p1a);
        mask_s[row][a] = 1.0f;
        sel_s[row][0] = p0a;
        sel_s[row][1] = p1a;
      }
    }
    // ---- gates(s+1) write from D regs (chains long since drained) ----
    if (s + 1 < Tt && lane < 16) {
      int c0 = (w << 5) + lane;
      #pragma unroll
      for (int rr = 0; rr < 4; ++rr) {
        gates_s[rr][c0] = d0[rr];
        gates_s[rr][c0 + 16] = d1[rr];
      }
    }
  }
  __syncthreads();

  // ---- epilogue: collapsed critic + tour length ----
  if (w < 4) {
    int r = w, b = blk * 4 + r;
    float p0 = sel_s[r][0], p1 = sel_s[r][1];
    float4 ct0 = ((float4*)ct_s)[lane];
    float4 ct1 = ((float4*)ct_s)[64 + lane];
    float t1a = fmaxf(fmaf(p0, ct0.x, fmaf(p1, ct0.y, ct0.z)), 0.f);
    float t1b = fmaxf(fmaf(p0, ct1.x, fmaf(p1, ct1.y, ct1.z)), 0.f);
    float sv = xsum(t1a * ct0.w + t1b * ct1.w);
    if (lane == 0) out[OFF_V + b] = sv + b2[0];
    float rr = 0.f;
    if (lane < Npt) {
      float2 c0 = ((float2*)ch_s)[r * Npt + lane];
      float2 c1 = ((float2*)ch_s)[r * Npt + ((lane == Npt - 1) ? 0 : lane + 1)];
      float dx = c1.x - c0.x, dy = c1.y - c0.y;
      rr = sqrtf(dx * dx + dy * dy + 1e-10f);
    }
    rr = xsum(rr);
    if (lane == 0) out[OFF_R + b] = rr;
  }
}

extern "C" void kernel_launch(void* const* d_in, const int* in_sizes, int n_in,
                              void* d_out, int out_size, void* d_ws, size_t ws_size,
                              hipStream_t stream) {
  (void)in_sizes; (void)n_in; (void)out_size; (void)ws_size;
  const float* ip    = (const float*)d_in[0];
  const float* Wemb  = (const float*)d_in[1];
  const float* bemb  = (const float*)d_in[2];
  const float* dinit = (const float*)d_in[3];
  const float* Wi    = (const float*)d_in[4];
  const float* Wh    = (const float*)d_in[5];
  const float* bl    = (const float*)d_in[6];
  const float* Wqg   = (const float*)d_in[7];
  const float* Wrg   = (const float*)d_in[8];
  const float* vg    = (const float*)d_in[9];
  const float* Wqp   = (const float*)d_in[10];
  const float* Wrp   = (const float*)d_in[11];
  const float* vp    = (const float*)d_in[12];
  // d_in[13..16], d_in[18] dead: critic N=1 softmax == 1 => hy = e_c
  const float* Wrc   = (const float*)d_in[17];
  const float* W1    = (const float*)d_in[19];
  const float* b1    = (const float*)d_in[20];
  const float* W2    = (const float*)d_in[21];
  const float* b2    = (const float*)d_in[22];
  float* out = (float*)d_out;
  float* ws  = (float*)d_ws;

  k_pre<<<1, 512, 0, stream>>>(Wemb, bemb, dinit, Wi, bl, Wqp, Wrg, Wrp,
                               vg, vp, Wrc, W1, b1, W2, ws);
  k_mega<<<256, 1024, 0, stream>>>(ip, Wh, Wqg, b2, ws, out);
}